// Round 3
// baseline (231.022 us; speedup 1.0000x reference)
//
#include <hip/hip_runtime.h>
#include <math.h>

static constexpr int BATCH = 32;
static constexpr int SEQ   = 4096;
static constexpr int HID   = 1024;
static constexpr int PSTRIDE = HID + 8;   // ctx[1024] + m + l (+pad, keeps 16B alignment)

// -------- Pass 1: fused scores + online-softmax context partials --------
// grid = BATCH*NCHUNK blocks, 256 threads (4 waves).
// Each wave streams RPW consecutive rows of enc[b] in row-PAIRS, with an
// explicit 2-deep register double-buffer (P/Q): loads for pair k+1 are issued
// BEFORE computing pair k, so 8-16 KB/wave stays outstanding continuously and
// the dot/shfl/exp compute shadow is hidden under in-flight loads.
template<int NCHUNK>
__global__ __launch_bounds__(256, 4)
void attn_fused_pass1(const float* __restrict__ enc,
                      const float* __restrict__ dec,
                      float* __restrict__ raw_scores,   // [B,S] = weights region of d_out
                      float* __restrict__ partials)     // [B*NCHUNK][PSTRIDE]
{
    constexpr int RC    = SEQ / NCHUNK;   // rows per chunk
    constexpr int RPW   = RC / 4;         // rows per wave
    constexpr int NPAIR = RPW / 2;        // row-pairs per wave
    static_assert(NPAIR >= 2 && (NPAIR % 2) == 0, "need even pair count >= 2");

    const int b     = blockIdx.x / NCHUNK;
    const int chunk = blockIdx.x % NCHUNK;
    const int tid   = threadIdx.x;
    const int w     = tid >> 6;
    const int lane  = tid & 63;

    __shared__ float s_dec[HID];
    __shared__ float s_ctx[4][HID];
    __shared__ float s_m[4], s_l[4];

    // stage dec[b] (4 KB) then keep this lane's 16-float fragment in registers
    ((float4*)s_dec)[tid] = ((const float4*)(dec + (size_t)b * HID))[tid];
    __syncthreads();
    const float4* sd = (const float4*)s_dec;
    const float4 d0 = sd[lane], d1 = sd[lane + 64], d2 = sd[lane + 128], d3 = sd[lane + 192];

    float m = -INFINITY, l = 0.f;
    float4 c0 = make_float4(0.f, 0.f, 0.f, 0.f);
    float4 c1 = c0, c2 = c0, c3 = c0;

    const int row0 = chunk * RC + w * RPW;
    const float4* base = (const float4*)(enc + ((size_t)b * SEQ + row0) * HID);
    float* sout = raw_scores + (size_t)b * SEQ + row0;

    float4 pa0, pa1, pa2, pa3, pb0, pb1, pb2, pb3;   // buffer P
    float4 qa0, qa1, qa2, qa3, qb0, qb1, qb2, qb3;   // buffer Q

#define LOAD_PAIR(A0, A1, A2, A3, B0, B1, B2, B3, pair)                        \
    do {                                                                       \
        const float4* _ra = base + (size_t)(2 * (pair)) * (HID / 4);           \
        const float4* _rb = _ra + (HID / 4);                                   \
        A0 = _ra[lane];       A1 = _ra[lane + 64];                             \
        A2 = _ra[lane + 128]; A3 = _ra[lane + 192];                            \
        B0 = _rb[lane];       B1 = _rb[lane + 64];                             \
        B2 = _rb[lane + 128]; B3 = _rb[lane + 192];                            \
    } while (0)

#define COMP_PAIR(A0, A1, A2, A3, B0, B1, B2, B3, pair)                        \
    do {                                                                       \
        float tA0 = A0.x*d0.x + A0.y*d0.y + A0.z*d0.z + A0.w*d0.w;             \
        float tA1 = A1.x*d1.x + A1.y*d1.y + A1.z*d1.z + A1.w*d1.w;             \
        float tA2 = A2.x*d2.x + A2.y*d2.y + A2.z*d2.z + A2.w*d2.w;             \
        float tA3 = A3.x*d3.x + A3.y*d3.y + A3.z*d3.z + A3.w*d3.w;             \
        float tB0 = B0.x*d0.x + B0.y*d0.y + B0.z*d0.z + B0.w*d0.w;             \
        float tB1 = B1.x*d1.x + B1.y*d1.y + B1.z*d1.z + B1.w*d1.w;             \
        float tB2 = B2.x*d2.x + B2.y*d2.y + B2.z*d2.z + B2.w*d2.w;             \
        float tB3 = B3.x*d3.x + B3.y*d3.y + B3.z*d3.z + B3.w*d3.w;             \
        float tA = (tA0 + tA1) + (tA2 + tA3);                                  \
        float tB = (tB0 + tB1) + (tB2 + tB3);                                  \
        _Pragma("unroll")                                                      \
        for (int off = 32; off > 0; off >>= 1) {                               \
            tA += __shfl_xor(tA, off, 64);                                     \
            tB += __shfl_xor(tB, off, 64);                                     \
        }                                                                      \
        if (lane == 0) {                                                       \
            float2 _s2; _s2.x = tA; _s2.y = tB;                                \
            *(float2*)(sout + 2 * (pair)) = _s2;                               \
        }                                                                      \
        const float mn = fmaxf(m, fmaxf(tA, tB));                              \
        if (mn > m) {                                                          \
            const float sc = __expf(m - mn);                                   \
            l *= sc;                                                           \
            c0.x*=sc; c0.y*=sc; c0.z*=sc; c0.w*=sc;                            \
            c1.x*=sc; c1.y*=sc; c1.z*=sc; c1.w*=sc;                            \
            c2.x*=sc; c2.y*=sc; c2.z*=sc; c2.w*=sc;                            \
            c3.x*=sc; c3.y*=sc; c3.z*=sc; c3.w*=sc;                            \
            m = mn;                                                            \
        }                                                                      \
        const float pA = __expf(tA - m);                                       \
        const float pB = __expf(tB - m);                                       \
        l += pA + pB;                                                          \
        c0.x += pA*A0.x + pB*B0.x; c0.y += pA*A0.y + pB*B0.y;                  \
        c0.z += pA*A0.z + pB*B0.z; c0.w += pA*A0.w + pB*B0.w;                  \
        c1.x += pA*A1.x + pB*B1.x; c1.y += pA*A1.y + pB*B1.y;                  \
        c1.z += pA*A1.z + pB*B1.z; c1.w += pA*A1.w + pB*B1.w;                  \
        c2.x += pA*A2.x + pB*B2.x; c2.y += pA*A2.y + pB*B2.y;                  \
        c2.z += pA*A2.z + pB*B2.z; c2.w += pA*A2.w + pB*B2.w;                  \
        c3.x += pA*A3.x + pB*B3.x; c3.y += pA*A3.y + pB*B3.y;                  \
        c3.z += pA*A3.z + pB*B3.z; c3.w += pA*A3.w + pB*B3.w;                  \
    } while (0)

    // software pipeline: prologue loads pair 0; each loop iteration handles
    // two pairs, always issuing the next pair's loads before computing.
    LOAD_PAIR(pa0, pa1, pa2, pa3, pb0, pb1, pb2, pb3, 0);
    for (int j = 0; j < NPAIR / 2 - 1; ++j) {
        LOAD_PAIR(qa0, qa1, qa2, qa3, qb0, qb1, qb2, qb3, 2 * j + 1);
        COMP_PAIR(pa0, pa1, pa2, pa3, pb0, pb1, pb2, pb3, 2 * j);
        LOAD_PAIR(pa0, pa1, pa2, pa3, pb0, pb1, pb2, pb3, 2 * j + 2);
        COMP_PAIR(qa0, qa1, qa2, qa3, qb0, qb1, qb2, qb3, 2 * j + 1);
    }
    LOAD_PAIR(qa0, qa1, qa2, qa3, qb0, qb1, qb2, qb3, NPAIR - 1);
    COMP_PAIR(pa0, pa1, pa2, pa3, pb0, pb1, pb2, pb3, NPAIR - 2);
    COMP_PAIR(qa0, qa1, qa2, qa3, qb0, qb1, qb2, qb3, NPAIR - 1);

#undef LOAD_PAIR
#undef COMP_PAIR

    // ---- combine the 4 waves of this block ----
    if (lane == 0) { s_m[w] = m; s_l[w] = l; }
    __syncthreads();
    const float mg = fmaxf(fmaxf(s_m[0], s_m[1]), fmaxf(s_m[2], s_m[3]));
    const float f  = __expf(m - mg);   // wave-uniform
    float4* sc4 = (float4*)s_ctx[w];
    float4 t0 = c0, t1 = c1, t2 = c2, t3 = c3;
    t0.x*=f; t0.y*=f; t0.z*=f; t0.w*=f;
    t1.x*=f; t1.y*=f; t1.z*=f; t1.w*=f;
    t2.x*=f; t2.y*=f; t2.z*=f; t2.w*=f;
    t3.x*=f; t3.y*=f; t3.z*=f; t3.w*=f;
    sc4[lane]       = t0;
    sc4[lane + 64]  = t1;
    sc4[lane + 128] = t2;
    sc4[lane + 192] = t3;
    __syncthreads();

    float lb = 0.f;
    #pragma unroll
    for (int i = 0; i < 4; ++i) lb += s_l[i] * __expf(s_m[i] - mg);

    float* pout = partials + (size_t)(b * NCHUNK + chunk) * PSTRIDE;
    const float4 v0 = ((const float4*)s_ctx[0])[tid];
    const float4 v1 = ((const float4*)s_ctx[1])[tid];
    const float4 v2 = ((const float4*)s_ctx[2])[tid];
    const float4 v3 = ((const float4*)s_ctx[3])[tid];
    float4 sum;
    sum.x = (v0.x + v1.x) + (v2.x + v3.x);
    sum.y = (v0.y + v1.y) + (v2.y + v3.y);
    sum.z = (v0.z + v1.z) + (v2.z + v3.z);
    sum.w = (v0.w + v1.w) + (v2.w + v3.w);
    ((float4*)pout)[tid] = sum;
    if (tid == 0) { pout[HID] = mg; pout[HID + 1] = lb; }
}

// -------- Pass 2: cross-chunk combine + weights normalization --------
// grid = BATCH * 8 blocks; each block redundantly recomputes the cheap
// (m,l) combine; sub-block 0 writes context, all 8 split the weights row.
template<int NCHUNK>
__global__ __launch_bounds__(256)
void attn_pass2(const float* __restrict__ partials,
                float* __restrict__ out_ctx,    // [B,H]
                float* __restrict__ weights)    // [B,S] in-place raw->softmax
{
    const int b   = blockIdx.x >> 3;
    const int sub = blockIdx.x & 7;
    const int tid = threadIdx.x;
    __shared__ float sm[NCHUNK], sl[NCHUNK];
    if (tid < NCHUNK) {
        const float* p = partials + (size_t)(b * NCHUNK + tid) * PSTRIDE;
        sm[tid] = p[HID];
        sl[tid] = p[HID + 1];
    }
    __syncthreads();

    float mg = -INFINITY;
    #pragma unroll
    for (int c = 0; c < NCHUNK; ++c) mg = fmaxf(mg, sm[c]);
    float lg = 0.f;
    #pragma unroll
    for (int c = 0; c < NCHUNK; ++c) lg += sl[c] * __expf(sm[c] - mg);
    const float inv = 1.f / lg;

    if (sub == 0) {
        // context: one float4 per thread (H = 1024 = 256 float4)
        float4 acc = make_float4(0.f, 0.f, 0.f, 0.f);
        #pragma unroll 4
        for (int c = 0; c < NCHUNK; ++c) {
            const float4* p4 = (const float4*)(partials + (size_t)(b * NCHUNK + c) * PSTRIDE);
            const float fc = __expf(sm[c] - mg);
            const float4 v = p4[tid];
            acc.x += fc * v.x; acc.y += fc * v.y; acc.z += fc * v.z; acc.w += fc * v.w;
        }
        acc.x *= inv; acc.y *= inv; acc.z *= inv; acc.w *= inv;
        ((float4*)(out_ctx + (size_t)b * HID))[tid] = acc;
    }

    // weights: normalize raw scores in place, SEQ/8 = 512 per sub-block
    float* wrow = weights + (size_t)b * SEQ;
    const int s0 = sub * (SEQ / 8);
    #pragma unroll
    for (int i = 0; i < SEQ / 8 / 256; ++i) {
        const int s = s0 + i * 256 + tid;
        wrow[s] = __expf(wrow[s] - mg) * inv;
    }
}

extern "C" void kernel_launch(void* const* d_in, const int* in_sizes, int n_in,
                              void* d_out, int out_size, void* d_ws, size_t ws_size,
                              hipStream_t stream) {
    const float* hidden = (const float*)d_in[0];          // [2, 32, 1024]
    const float* enc    = (const float*)d_in[1];          // [32, 4096, 1024]
    const float* dec    = hidden + (size_t)BATCH * HID;   // hidden[-1] -> [32, 1024]

    float* out     = (float*)d_out;
    float* ctx_out = out;                                 // [32, 1024]
    float* w_out   = out + (size_t)BATCH * HID;           // [32, 4096]
    float* partials = (float*)d_ws;

#define LAUNCH_NC(NC)                                                              \
    do {                                                                           \
        attn_fused_pass1<NC><<<BATCH * NC, 256, 0, stream>>>(enc, dec, w_out,      \
                                                             partials);            \
        attn_pass2<NC><<<BATCH * 8, 256, 0, stream>>>(partials, ctx_out, w_out);   \
    } while (0)

    const size_t per_chunk_bytes = (size_t)BATCH * PSTRIDE * sizeof(float);
    if      (ws_size >= 32 * per_chunk_bytes) LAUNCH_NC(32);
    else if (ws_size >= 16 * per_chunk_bytes) LAUNCH_NC(16);
    else if (ws_size >=  8 * per_chunk_bytes) LAUNCH_NC(8);
    else if (ws_size >=  4 * per_chunk_bytes) LAUNCH_NC(4);
    else if (ws_size >=  2 * per_chunk_bytes) LAUNCH_NC(2);
    else                                      LAUNCH_NC(1);
#undef LAUNCH_NC
}